// Round 5
// baseline (365.874 us; speedup 1.0000x reference)
//
#include <hip/hip_runtime.h>
#include <math.h>
#include <stdint.h>

#define B_ 16
#define D_ 1024
#define T_ 4096
#define CS_ 1024
#define CD_ 8

// ---------- numpy-mimicking fp32 helpers ----------
__device__ __forceinline__ float f_tree8(const float r[8]) {
  return __fadd_rn(
      __fadd_rn(__fadd_rn(r[0], r[1]), __fadd_rn(r[2], r[3])),
      __fadd_rn(__fadd_rn(r[4], r[5]), __fadd_rn(r[6], r[7])));
}
__device__ __forceinline__ float f_sumsq8(const float x[8]) {
  float s[8];
#pragma unroll
  for (int k = 0; k < 8; ++k) s[k] = __fmul_rn(x[k], x[k]);
  return f_tree8(s);
}

// ---------- setup: normalize W_in, W_out, codebook; pack tables ----------
// ws layout:
//   WTd  : double[1024][8]   (W_in^T, fp32-rounded widened to f64)  @ 0      (65536 B)
//   cb16 : float [1024][16]  ({cbn[8], scb, pad})                   @ 65536  (65536 B)
//   wo16 : float [1024][16]  ({woutn[8], b_out, pad})               @ 131072 (65536 B)
//   lossp: float [1024]                                             @ 196608 (4096 B)
__global__ __launch_bounds__(1024) void vq_setup(
    const float* __restrict__ cb, const float* __restrict__ g_in,
    const float* __restrict__ v_in, const float* __restrict__ g_out,
    const float* __restrict__ v_out, const float* __restrict__ b_out,
    double* __restrict__ WTd, float* __restrict__ cb16,
    float* __restrict__ wo16) {
  __shared__ float sv[8 * 1024];
  __shared__ float leafs[64];
  __shared__ float den[8];
  const int tid = threadIdx.x;

  for (int i = tid; i < 8 * 1024; i += 1024) sv[i] = v_in[i];
  __syncthreads();

  // numpy pairwise_sum(1024): 8 leaf blocks of 128 (8-accumulator pattern),
  // combined with the same binary tree as tree8.
  if (tid < 64) {
    const int c = tid >> 3, l = tid & 7;
    const float* a = sv + c * 1024 + l * 128;
    float r[8];
#pragma unroll
    for (int k = 0; k < 8; ++k) r[k] = __fmul_rn(a[k], a[k]);
    for (int i = 8; i < 128; i += 8) {
#pragma unroll
      for (int k = 0; k < 8; ++k)
        r[k] = __fadd_rn(r[k], __fmul_rn(a[i + k], a[i + k]));
    }
    leafs[c * 8 + l] = f_tree8(r);
  }
  __syncthreads();
  if (tid < 8) {
    const float* L = leafs + tid * 8;
    float lr[8];
#pragma unroll
    for (int k = 0; k < 8; ++k) lr[k] = L[k];
    const float s = f_tree8(lr);
    den[tid] = fmaxf(__fsqrt_rn(s), 1e-12f);
  }
  __syncthreads();

  if (tid < 1024) {
#pragma unroll
    for (int c = 0; c < 8; ++c) {
      const float w = __fdiv_rn(__fmul_rn(g_in[c], sv[c * 1024 + tid]), den[c]);
      WTd[tid * 8 + c] = (double)w;
    }
    {
      const float* cr = cb + tid * 8;
      float q[8];
#pragma unroll
      for (int c = 0; c < 8; ++c) q[c] = cr[c];
      const float nn = f_sumsq8(q);
      const float dd = fmaxf(__fsqrt_rn(nn), 1e-12f);
      float qn[8];
#pragma unroll
      for (int c = 0; c < 8; ++c) {
        qn[c] = __fdiv_rn(q[c], dd);
        cb16[tid * 16 + c] = qn[c];
      }
      cb16[tid * 16 + 8] = f_sumsq8(qn);
#pragma unroll
      for (int c = 9; c < 16; ++c) cb16[tid * 16 + c] = 0.f;
    }
    {
      const float* vr = v_out + tid * 8;
      float w[8];
#pragma unroll
      for (int c = 0; c < 8; ++c) w[c] = vr[c];
      const float n2 = f_sumsq8(w);
      const float d2 = fmaxf(__fsqrt_rn(n2), 1e-12f);
      const float go = g_out[tid];
#pragma unroll
      for (int c = 0; c < 8; ++c)
        wo16[tid * 16 + c] = __fdiv_rn(__fmul_rn(go, w[c]), d2);
      wo16[tid * 16 + 8] = b_out[tid];
#pragma unroll
      for (int c = 9; c < 16; ++c) wo16[tid * 16 + c] = 0.f;
    }
  }
}

// Pin a pointer into VGPRs so divergence analysis treats it as non-uniform:
// all downstream loads use the vector path (vmcnt, in-order, pipelined)
// instead of s_load (whose lgkmcnt returns out-of-order and forces
// full-drain waits that serialize the loop).
__device__ __forceinline__ const void* vgpr_pin(const void* p) {
  uint64_t a = (uint64_t)p;
  asm volatile("" : "+v"(a));
  return (const void*)a;
}

// ---------- main kernel ----------
// Grid: 1024 blocks x 512 threads (8 waves). Block owns 64 consecutive t of
// one b. Wave q (=tid>>6, wave-uniform) handles the same 64 t as the other
// waves but d/code OCTANT [q*128, q*128+128).
// Table rows (WTd/cb16/wo16) are read via pinned-VGPR vector loads
// (broadcast, L1/L2-hot). z loads are double-buffered 8-deep per wave.
__global__ __launch_bounds__(512, 4) void vq_main(
    const float* __restrict__ z, const float* __restrict__ cbraw,
    const float* __restrict__ b_in, const double* __restrict__ WTd,
    const float* __restrict__ cb16, const float* __restrict__ wo16,
    float* __restrict__ out, float* __restrict__ oidx,
    float* __restrict__ lossp) {
  __shared__ double accb[4096];  // 32 KB, reused for candidate combine
  const int tid = threadIdx.x;
  const int q0 = __builtin_amdgcn_readfirstlane(tid >> 6);  // wave id 0..7
  const int tl = tid & 63;
  const int blk = blockIdx.x;  // 1024 = 16 b * 64 tiles
  const int b = blk >> 6;
  const int tile = blk & 63;
  const int t = tile * 64 + tl;

  // ---- phase 1: partial z_e in f64 over this wave's 128-d octant ----
  const float* zp = z + ((size_t)b * D_ + (size_t)q0 * 128) * T_ + t;
  const double* wdv = (const double*)vgpr_pin(WTd + (size_t)q0 * 1024);

  double acc[8];
#pragma unroll
  for (int c = 0; c < 8; ++c) acc[c] = 0.0;

  float zA[8], zB[8];
#pragma unroll
  for (int u = 0; u < 8; ++u) zA[u] = zp[(size_t)u * T_];

#pragma unroll
  for (int dc = 0; dc < 128; dc += 16) {
    // prefetch group B (d = dc+8 .. dc+15)
#pragma unroll
    for (int u = 0; u < 8; ++u) zB[u] = zp[(size_t)(dc + 8 + u) * T_];
    // compute group A
#pragma unroll
    for (int u = 0; u < 8; ++u) {
      const double2* w2 = (const double2*)(wdv + (size_t)(dc + u) * 8);
      const double2 w01 = w2[0], w23 = w2[1], w45 = w2[2], w67 = w2[3];
      const double zd = (double)zA[u];
      acc[0] = fma(zd, w01.x, acc[0]);
      acc[1] = fma(zd, w01.y, acc[1]);
      acc[2] = fma(zd, w23.x, acc[2]);
      acc[3] = fma(zd, w23.y, acc[3]);
      acc[4] = fma(zd, w45.x, acc[4]);
      acc[5] = fma(zd, w45.y, acc[5]);
      acc[6] = fma(zd, w67.x, acc[6]);
      acc[7] = fma(zd, w67.y, acc[7]);
    }
    // prefetch group A for next chunk (d = dc+16 .. dc+23)
    if (dc + 16 < 128) {
#pragma unroll
      for (int u = 0; u < 8; ++u) zA[u] = zp[(size_t)(dc + 16 + u) * T_];
    }
    // compute group B
#pragma unroll
    for (int u = 0; u < 8; ++u) {
      const double2* w2 = (const double2*)(wdv + (size_t)(dc + 8 + u) * 8);
      const double2 w01 = w2[0], w23 = w2[1], w45 = w2[2], w67 = w2[3];
      const double zd = (double)zB[u];
      acc[0] = fma(zd, w01.x, acc[0]);
      acc[1] = fma(zd, w01.y, acc[1]);
      acc[2] = fma(zd, w23.x, acc[2]);
      acc[3] = fma(zd, w23.y, acc[3]);
      acc[4] = fma(zd, w45.x, acc[4]);
      acc[5] = fma(zd, w45.y, acc[5]);
      acc[6] = fma(zd, w67.x, acc[6]);
      acc[7] = fma(zd, w67.y, acc[7]);
    }
  }

  // transposed combine buffer: accb[c][tid] (stride 8B across lanes: free)
#pragma unroll
  for (int c = 0; c < 8; ++c) accb[c * 512 + tid] = acc[c];
  __syncthreads();

  double tot[8];
#pragma unroll
  for (int c = 0; c < 8; ++c) {
    const double* row = accb + c * 512 + tl;
    double s = row[0];
#pragma unroll
    for (int qq = 1; qq < 8; ++qq) s = s + row[qq * 64];
    tot[c] = s;
  }
  __syncthreads();  // accb dead (will be reused)

  // materialize fp32 z_e (+ b_in), normalize (numpy-mimicked)
  float e[8], en[8];
#pragma unroll
  for (int c = 0; c < 8; ++c) e[c] = __fadd_rn((float)tot[c], b_in[c]);
  const float n2 = f_sumsq8(e);
  const float dn = fmaxf(__fsqrt_rn(n2), 1e-12f);
#pragma unroll
  for (int c = 0; c < 8; ++c) en[c] = __fdiv_rn(e[c], dn);
  const float s_enc = f_sumsq8(en);

  // ---- phase 2: nearest code over this wave's 128-code octant ----
  const int j0 = q0 * 128;
  float best = INFINITY;
  int bj = j0;
  {
    const float* cbv = (const float*)vgpr_pin(cb16 + (size_t)j0 * 16);
#pragma unroll 4
    for (int jj = 0; jj < 128; ++jj) {
      const float4* r4 = (const float4*)(cbv + jj * 16);
      const float4 lo = r4[0], hi = r4[1];
      const float sc = cbv[jj * 16 + 8];
      float dot = 0.f;
      dot = fmaf(en[0], lo.x, dot);
      dot = fmaf(en[1], lo.y, dot);
      dot = fmaf(en[2], lo.z, dot);
      dot = fmaf(en[3], lo.w, dot);
      dot = fmaf(en[4], hi.x, dot);
      dot = fmaf(en[5], hi.y, dot);
      dot = fmaf(en[6], hi.z, dot);
      dot = fmaf(en[7], hi.w, dot);
      const float dist = __fadd_rn(__fsub_rn(s_enc, __fmul_rn(2.0f, dot)), sc);
      if (dist < best) { best = dist; bj = j0 + jj; }
    }
  }

  // candidate combine (SoA in reused LDS; stride 4B: conflict-free)
  float* distf = (float*)accb;              // 512 f32
  int* candj = (int*)((char*)accb + 2048);  // 512 i32
  distf[tid] = best;
  candj[tid] = bj;
  __syncthreads();

  float bd = distf[tl];
  int bi = candj[tl];
#pragma unroll
  for (int qq = 1; qq < 8; ++qq) {
    const float dd = distf[qq * 64 + tl];
    const int jj = candj[qq * 64 + tl];
    if (dd < bd) { bd = dd; bi = jj; }  // strict <: lower octant wins ties
  }

  if (tid < 64) oidx[(size_t)b * T_ + t] = (float)bi;

  // raw codebook row for loss + back-projection (divergent 32B gather)
  float cq[8];
  {
    const float* cp = cbraw + (size_t)bi * 8;
#pragma unroll
    for (int c = 0; c < 8; ++c) cq[c] = cp[c];
  }

  // ---- loss partial (wave 0 only; all waves hold identical e, cq) ----
  if (tid < 64) {
    float lsum = 0.f;
#pragma unroll
    for (int c = 0; c < 8; ++c) {
      const float df = __fsub_rn(e[c], cq[c]);
      lsum = fmaf(df, df, lsum);
    }
#pragma unroll
    for (int off = 32; off > 0; off >>= 1)
      lsum += __shfl_down(lsum, off, 64);
    if (tl == 0) lossp[blk] = lsum;
  }

  // ---- phase 3: out[b,d,t] = dot8(cq, W_out_n[d]) + b_out[d] ----
  float* op = out + ((size_t)b * D_ + (size_t)q0 * 128) * T_ + t;
  const float* wov = (const float*)vgpr_pin(wo16 + (size_t)q0 * 2048);
#pragma unroll 4
  for (int d = 0; d < 128; ++d) {
    const float4* r4 = (const float4*)(wov + d * 16);
    const float4 lo = r4[0], hi = r4[1];
    const float bo = wov[d * 16 + 8];
    float dot = 0.f;
    dot = fmaf(cq[0], lo.x, dot);
    dot = fmaf(cq[1], lo.y, dot);
    dot = fmaf(cq[2], lo.z, dot);
    dot = fmaf(cq[3], lo.w, dot);
    dot = fmaf(cq[4], hi.x, dot);
    dot = fmaf(cq[5], hi.y, dot);
    dot = fmaf(cq[6], hi.z, dot);
    dot = fmaf(cq[7], hi.w, dot);
    op[(size_t)d * T_] = __fadd_rn(dot, bo);
  }
}

// ---------- finalize loss ----------
__global__ __launch_bounds__(64) void vq_fin(const float* __restrict__ lossp,
                                             float* __restrict__ oloss) {
  const int tid = threadIdx.x;
  if (tid < B_) {
    float s = 0.f;
    for (int i = 0; i < 64; ++i) s += lossp[tid * 64 + i];
    oloss[tid] = s * (1.25f / 32768.0f);
  }
}

extern "C" void kernel_launch(void* const* d_in, const int* in_sizes, int n_in,
                              void* d_out, int out_size, void* d_ws,
                              size_t ws_size, hipStream_t stream) {
  (void)in_sizes; (void)n_in; (void)out_size; (void)ws_size;
  const float* z = (const float*)d_in[0];
  const float* cb = (const float*)d_in[1];
  const float* g_in = (const float*)d_in[2];
  const float* v_in = (const float*)d_in[3];
  const float* b_in = (const float*)d_in[4];
  const float* g_out = (const float*)d_in[5];
  const float* v_out = (const float*)d_in[6];
  const float* b_out = (const float*)d_in[7];
  float* out = (float*)d_out;

  char* ws = (char*)d_ws;
  double* WTd = (double*)ws;              // 65536 B
  float* cb16 = (float*)(ws + 65536);     // 65536 B
  float* wo16 = (float*)(ws + 131072);    // 65536 B
  float* lossp = (float*)(ws + 196608);   // 4096 B

  float* oidx = out + (size_t)B_ * D_ * T_;
  float* oloss = oidx + (size_t)B_ * T_;

  vq_setup<<<1, 1024, 0, stream>>>(cb, g_in, v_in, g_out, v_out, b_out, WTd,
                                   cb16, wo16);
  vq_main<<<1024, 512, 0, stream>>>(z, cb, b_in, WTd, cb16, wo16, out, oidx,
                                    lossp);
  vq_fin<<<1, 64, 0, stream>>>(lossp, oloss);
}

// Round 6
// 164.539 us; speedup vs baseline: 2.2236x; 2.2236x over previous
//
#include <hip/hip_runtime.h>
#include <math.h>
#include <stdint.h>

#define B_ 16
#define D_ 1024
#define T_ 4096
#define CS_ 1024
#define CD_ 8

// ---------- numpy-mimicking fp32 helpers ----------
__device__ __forceinline__ float f_tree8(const float r[8]) {
  return __fadd_rn(
      __fadd_rn(__fadd_rn(r[0], r[1]), __fadd_rn(r[2], r[3])),
      __fadd_rn(__fadd_rn(r[4], r[5]), __fadd_rn(r[6], r[7])));
}
__device__ __forceinline__ float f_sumsq8(const float x[8]) {
  float s[8];
#pragma unroll
  for (int k = 0; k < 8; ++k) s[k] = __fmul_rn(x[k], x[k]);
  return f_tree8(s);
}

// ---------- setup: normalize W_in, W_out, codebook; pack tables ----------
// ws layout:
//   WTd  : double[1024][8]   (W_in^T, fp32-rounded widened to f64)  @ 0      (65536 B)
//   cb16 : float [1024][16]  ({cbn[8], scb, pad})                   @ 65536  (65536 B)
//   wo16 : float [1024][16]  ({woutn[8], b_out, pad})               @ 131072 (65536 B)
//   lossp: float [512]                                              @ 196608 (2048 B)
__global__ __launch_bounds__(1024) void vq_setup(
    const float* __restrict__ cb, const float* __restrict__ g_in,
    const float* __restrict__ v_in, const float* __restrict__ g_out,
    const float* __restrict__ v_out, const float* __restrict__ b_out,
    double* __restrict__ WTd, float* __restrict__ cb16,
    float* __restrict__ wo16) {
  __shared__ float sv[8 * 1024];
  __shared__ float leafs[64];
  __shared__ float den[8];
  const int tid = threadIdx.x;

  for (int i = tid; i < 8 * 1024; i += 1024) sv[i] = v_in[i];
  __syncthreads();

  // numpy pairwise_sum(1024): 8 leaf blocks of 128 (8-accumulator pattern),
  // combined with the same binary tree as tree8.
  if (tid < 64) {
    const int c = tid >> 3, l = tid & 7;
    const float* a = sv + c * 1024 + l * 128;
    float r[8];
#pragma unroll
    for (int k = 0; k < 8; ++k) r[k] = __fmul_rn(a[k], a[k]);
    for (int i = 8; i < 128; i += 8) {
#pragma unroll
      for (int k = 0; k < 8; ++k)
        r[k] = __fadd_rn(r[k], __fmul_rn(a[i + k], a[i + k]));
    }
    leafs[c * 8 + l] = f_tree8(r);
  }
  __syncthreads();
  if (tid < 8) {
    const float* L = leafs + tid * 8;
    float lr[8];
#pragma unroll
    for (int k = 0; k < 8; ++k) lr[k] = L[k];
    const float s = f_tree8(lr);
    den[tid] = fmaxf(__fsqrt_rn(s), 1e-12f);
  }
  __syncthreads();

  if (tid < 1024) {
#pragma unroll
    for (int c = 0; c < 8; ++c) {
      const float w = __fdiv_rn(__fmul_rn(g_in[c], sv[c * 1024 + tid]), den[c]);
      WTd[tid * 8 + c] = (double)w;
    }
    {
      const float* cr = cb + tid * 8;
      float q[8];
#pragma unroll
      for (int c = 0; c < 8; ++c) q[c] = cr[c];
      const float nn = f_sumsq8(q);
      const float dd = fmaxf(__fsqrt_rn(nn), 1e-12f);
      float qn[8];
#pragma unroll
      for (int c = 0; c < 8; ++c) {
        qn[c] = __fdiv_rn(q[c], dd);
        cb16[tid * 16 + c] = qn[c];
      }
      cb16[tid * 16 + 8] = f_sumsq8(qn);
#pragma unroll
      for (int c = 9; c < 16; ++c) cb16[tid * 16 + c] = 0.f;
    }
    {
      const float* vr = v_out + tid * 8;
      float w[8];
#pragma unroll
      for (int c = 0; c < 8; ++c) w[c] = vr[c];
      const float n2 = f_sumsq8(w);
      const float d2 = fmaxf(__fsqrt_rn(n2), 1e-12f);
      const float go = g_out[tid];
#pragma unroll
      for (int c = 0; c < 8; ++c)
        wo16[tid * 16 + c] = __fdiv_rn(__fmul_rn(go, w[c]), d2);
      wo16[tid * 16 + 8] = b_out[tid];
#pragma unroll
      for (int c = 9; c < 16; ++c) wo16[tid * 16 + c] = 0.f;
    }
  }
}

// ---------- main kernel ----------
// Grid: 512 blocks x 512 threads (8 waves). Block owns 128 consecutive t of
// one b; each LANE owns 2 consecutive t (float2 z loads / out stores).
// Wave q (=tid>>6, wave-uniform) covers the same 128 t as the other waves
// but d/code OCTANT [q*128, (q+1)*128). Tables via uniform s_load (scalar
// path, proven in R4); z via explicit 8-deep double-buffered float2 loads
// so ~8 VMEM loads stay in flight per wave (R4's depth was ~1-2 -> 2 TB/s).
__global__ __launch_bounds__(512, 4) void vq_main(
    const float* __restrict__ z, const float* __restrict__ cbraw,
    const float* __restrict__ b_in, const double* __restrict__ WTd,
    const float* __restrict__ cb16, const float* __restrict__ wo16,
    float* __restrict__ out, float* __restrict__ oidx,
    float* __restrict__ lossp) {
  __shared__ double accb[8192];  // 64 KB: f64 combine, reused for candidates
  const int tid = threadIdx.x;
  const int q0 = __builtin_amdgcn_readfirstlane(tid >> 6);  // wave id 0..7
  const int tl = tid & 63;
  const int blk = blockIdx.x;  // 512 = 16 b * 32 tiles
  const int b = blk >> 5;
  const int tile = blk & 31;
  const int t0 = tile * 128 + tl * 2;  // this lane's t-pair

  // ---- phase 1: partial z_e in f64 over this wave's 128-d octant ----
  const float2* zp2 =
      (const float2*)(z + ((size_t)b * D_ + (size_t)q0 * 128) * T_ + t0);
  const double* wd = WTd + (size_t)q0 * 1024;  // uniform -> s_load

  double acc0[8], acc1[8];
#pragma unroll
  for (int c = 0; c < 8; ++c) { acc0[c] = 0.0; acc1[c] = 0.0; }

  float2 zA[8], zB[8];
#pragma unroll
  for (int u = 0; u < 8; ++u) zA[u] = zp2[(size_t)u * (T_ / 2)];

#pragma unroll
  for (int dc = 0; dc < 128; dc += 16) {
    // prefetch group B (d = dc+8 .. dc+15)
#pragma unroll
    for (int u = 0; u < 8; ++u)
      zB[u] = zp2[(size_t)(dc + 8 + u) * (T_ / 2)];
    // compute group A
#pragma unroll
    for (int u = 0; u < 8; ++u) {
      const double* w = wd + (size_t)(dc + u) * 8;
      const double zx = (double)zA[u].x, zy = (double)zA[u].y;
#pragma unroll
      for (int c = 0; c < 8; ++c) {
        acc0[c] = fma(zx, w[c], acc0[c]);
        acc1[c] = fma(zy, w[c], acc1[c]);
      }
    }
    // prefetch group A for next chunk
    if (dc + 16 < 128) {
#pragma unroll
      for (int u = 0; u < 8; ++u)
        zA[u] = zp2[(size_t)(dc + 16 + u) * (T_ / 2)];
    }
    // compute group B
#pragma unroll
    for (int u = 0; u < 8; ++u) {
      const double* w = wd + (size_t)(dc + 8 + u) * 8;
      const double zx = (double)zB[u].x, zy = (double)zB[u].y;
#pragma unroll
      for (int c = 0; c < 8; ++c) {
        acc0[c] = fma(zx, w[c], acc0[c]);
        acc1[c] = fma(zy, w[c], acc1[c]);
      }
    }
  }

  // transposed combine buffer: accb2[c][tid] = {acc0,acc1} (16B/lane: clean)
  double2* accb2 = (double2*)accb;
#pragma unroll
  for (int c = 0; c < 8; ++c) {
    double2 v; v.x = acc0[c]; v.y = acc1[c];
    accb2[c * 512 + tid] = v;
  }
  __syncthreads();

  double tot0[8], tot1[8];
#pragma unroll
  for (int c = 0; c < 8; ++c) {
    const double2* row = accb2 + c * 512 + tl;
    double2 s = row[0];
#pragma unroll
    for (int qq = 1; qq < 8; ++qq) {
      const double2 v = row[qq * 64];
      s.x = s.x + v.x;  // ascending octant order: bit-identical to R4
      s.y = s.y + v.y;
    }
    tot0[c] = s.x; tot1[c] = s.y;
  }
  __syncthreads();  // accb dead (will be reused)

  // materialize fp32 z_e (+ b_in), normalize (numpy-mimicked), per t
  float e0[8], e1[8], en0[8], en1[8];
#pragma unroll
  for (int c = 0; c < 8; ++c) {
    e0[c] = __fadd_rn((float)tot0[c], b_in[c]);
    e1[c] = __fadd_rn((float)tot1[c], b_in[c]);
  }
  const float n20 = f_sumsq8(e0), n21 = f_sumsq8(e1);
  const float dn0 = fmaxf(__fsqrt_rn(n20), 1e-12f);
  const float dn1 = fmaxf(__fsqrt_rn(n21), 1e-12f);
#pragma unroll
  for (int c = 0; c < 8; ++c) {
    en0[c] = __fdiv_rn(e0[c], dn0);
    en1[c] = __fdiv_rn(e1[c], dn1);
  }
  const float s_enc0 = f_sumsq8(en0), s_enc1 = f_sumsq8(en1);

  // ---- phase 2: nearest code over this wave's 128-code octant ----
  const int j0 = q0 * 128;
  float best0 = INFINITY, best1 = INFINITY;
  int bj0 = j0, bj1 = j0;
  {
    const float* cbq = cb16 + (size_t)j0 * 16;  // uniform -> s_load
#pragma unroll 4
    for (int jj = 0; jj < 128; ++jj) {
      const float* row = cbq + jj * 16;
      const float4 lo = *(const float4*)(row);
      const float4 hi = *(const float4*)(row + 4);
      const float sc = row[8];
      float d0 = 0.f, d1 = 0.f;
      d0 = fmaf(en0[0], lo.x, d0); d1 = fmaf(en1[0], lo.x, d1);
      d0 = fmaf(en0[1], lo.y, d0); d1 = fmaf(en1[1], lo.y, d1);
      d0 = fmaf(en0[2], lo.z, d0); d1 = fmaf(en1[2], lo.z, d1);
      d0 = fmaf(en0[3], lo.w, d0); d1 = fmaf(en1[3], lo.w, d1);
      d0 = fmaf(en0[4], hi.x, d0); d1 = fmaf(en1[4], hi.x, d1);
      d0 = fmaf(en0[5], hi.y, d0); d1 = fmaf(en1[5], hi.y, d1);
      d0 = fmaf(en0[6], hi.z, d0); d1 = fmaf(en1[6], hi.z, d1);
      d0 = fmaf(en0[7], hi.w, d0); d1 = fmaf(en1[7], hi.w, d1);
      const float dist0 =
          __fadd_rn(__fsub_rn(s_enc0, __fmul_rn(2.0f, d0)), sc);
      const float dist1 =
          __fadd_rn(__fsub_rn(s_enc1, __fmul_rn(2.0f, d1)), sc);
      if (dist0 < best0) { best0 = dist0; bj0 = j0 + jj; }
      if (dist1 < best1) { best1 = dist1; bj1 = j0 + jj; }
    }
  }

  // candidate combine (SoA in reused LDS; 4B stride: conflict-free)
  float* distf0 = (float*)accb;                 // 512 f32
  int* candj0 = (int*)((char*)accb + 2048);     // 512 i32
  float* distf1 = (float*)((char*)accb + 4096); // 512 f32
  int* candj1 = (int*)((char*)accb + 6144);     // 512 i32
  distf0[tid] = best0; candj0[tid] = bj0;
  distf1[tid] = best1; candj1[tid] = bj1;
  __syncthreads();

  float bd0 = distf0[tl], bd1 = distf1[tl];
  int bi0 = candj0[tl], bi1 = candj1[tl];
#pragma unroll
  for (int qq = 1; qq < 8; ++qq) {
    const float dd0 = distf0[qq * 64 + tl];
    const int jj0v = candj0[qq * 64 + tl];
    if (dd0 < bd0) { bd0 = dd0; bi0 = jj0v; }  // strict <: low octant wins
    const float dd1 = distf1[qq * 64 + tl];
    const int jj1v = candj1[qq * 64 + tl];
    if (dd1 < bd1) { bd1 = dd1; bi1 = jj1v; }
  }

  if (tid < 64) {
    float2 iv; iv.x = (float)bi0; iv.y = (float)bi1;
    *(float2*)(oidx + (size_t)b * T_ + t0) = iv;
  }

  // raw codebook rows for loss + back-projection (divergent 32B gathers)
  float cq0[8], cq1[8];
  {
    const float* cp0 = cbraw + (size_t)bi0 * 8;
    const float* cp1 = cbraw + (size_t)bi1 * 8;
#pragma unroll
    for (int c = 0; c < 8; ++c) { cq0[c] = cp0[c]; cq1[c] = cp1[c]; }
  }

  // ---- loss partial (wave 0 only; all waves hold identical e, cq) ----
  if (tid < 64) {
    float lsum = 0.f;
#pragma unroll
    for (int c = 0; c < 8; ++c) {
      const float df0 = __fsub_rn(e0[c], cq0[c]);
      lsum = fmaf(df0, df0, lsum);
    }
#pragma unroll
    for (int c = 0; c < 8; ++c) {
      const float df1 = __fsub_rn(e1[c], cq1[c]);
      lsum = fmaf(df1, df1, lsum);
    }
#pragma unroll
    for (int off = 32; off > 0; off >>= 1)
      lsum += __shfl_down(lsum, off, 64);
    if (tl == 0) lossp[blk] = lsum;
  }

  // ---- phase 3: out[b,d,{t0,t0+1}] = dot8(cq, W_out_n[d]) + b_out[d] ----
  float2* op2 =
      (float2*)(out + ((size_t)b * D_ + (size_t)q0 * 128) * T_ + t0);
  const float* woq = wo16 + (size_t)q0 * 2048;  // uniform -> s_load
#pragma unroll 4
  for (int d = 0; d < 128; ++d) {
    const float* row = woq + d * 16;
    const float4 lo = *(const float4*)(row);
    const float4 hi = *(const float4*)(row + 4);
    const float bo = row[8];
    float d0 = 0.f, d1 = 0.f;
    d0 = fmaf(cq0[0], lo.x, d0); d1 = fmaf(cq1[0], lo.x, d1);
    d0 = fmaf(cq0[1], lo.y, d0); d1 = fmaf(cq1[1], lo.y, d1);
    d0 = fmaf(cq0[2], lo.z, d0); d1 = fmaf(cq1[2], lo.z, d1);
    d0 = fmaf(cq0[3], lo.w, d0); d1 = fmaf(cq1[3], lo.w, d1);
    d0 = fmaf(cq0[4], hi.x, d0); d1 = fmaf(cq1[4], hi.x, d1);
    d0 = fmaf(cq0[5], hi.y, d0); d1 = fmaf(cq1[5], hi.y, d1);
    d0 = fmaf(cq0[6], hi.z, d0); d1 = fmaf(cq1[6], hi.z, d1);
    d0 = fmaf(cq0[7], hi.w, d0); d1 = fmaf(cq1[7], hi.w, d1);
    float2 ov; ov.x = __fadd_rn(d0, bo); ov.y = __fadd_rn(d1, bo);
    op2[(size_t)d * (T_ / 2)] = ov;
  }
}

// ---------- finalize loss ----------
__global__ __launch_bounds__(64) void vq_fin(const float* __restrict__ lossp,
                                             float* __restrict__ oloss) {
  const int tid = threadIdx.x;
  if (tid < B_) {
    float s = 0.f;
    for (int i = 0; i < 32; ++i) s += lossp[tid * 32 + i];
    oloss[tid] = s * (1.25f / 32768.0f);
  }
}

extern "C" void kernel_launch(void* const* d_in, const int* in_sizes, int n_in,
                              void* d_out, int out_size, void* d_ws,
                              size_t ws_size, hipStream_t stream) {
  (void)in_sizes; (void)n_in; (void)out_size; (void)ws_size;
  const float* z = (const float*)d_in[0];
  const float* cb = (const float*)d_in[1];
  const float* g_in = (const float*)d_in[2];
  const float* v_in = (const float*)d_in[3];
  const float* b_in = (const float*)d_in[4];
  const float* g_out = (const float*)d_in[5];
  const float* v_out = (const float*)d_in[6];
  const float* b_out = (const float*)d_in[7];
  float* out = (float*)d_out;

  char* ws = (char*)d_ws;
  double* WTd = (double*)ws;              // 65536 B
  float* cb16 = (float*)(ws + 65536);     // 65536 B
  float* wo16 = (float*)(ws + 131072);    // 65536 B
  float* lossp = (float*)(ws + 196608);   // 2048 B

  float* oidx = out + (size_t)B_ * D_ * T_;
  float* oloss = oidx + (size_t)B_ * T_;

  vq_setup<<<1, 1024, 0, stream>>>(cb, g_in, v_in, g_out, v_out, b_out, WTd,
                                   cb16, wo16);
  vq_main<<<512, 512, 0, stream>>>(z, cb, b_in, WTd, cb16, wo16, out, oidx,
                                   lossp);
  vq_fin<<<1, 64, 0, stream>>>(lossp, oloss);
}

// Round 7
// 150.985 us; speedup vs baseline: 2.4232x; 1.0898x over previous
//
#include <hip/hip_runtime.h>
#include <math.h>
#include <stdint.h>

#define B_ 16
#define D_ 1024
#define T_ 4096
#define CS_ 1024
#define CD_ 8

// ---------- numpy-mimicking fp32 helpers ----------
__device__ __forceinline__ float f_tree8(const float r[8]) {
  return __fadd_rn(
      __fadd_rn(__fadd_rn(r[0], r[1]), __fadd_rn(r[2], r[3])),
      __fadd_rn(__fadd_rn(r[4], r[5]), __fadd_rn(r[6], r[7])));
}
__device__ __forceinline__ float f_sumsq8(const float x[8]) {
  float s[8];
#pragma unroll
  for (int k = 0; k < 8; ++k) s[k] = __fmul_rn(x[k], x[k]);
  return f_tree8(s);
}

// ---------- setup: normalize W_in, W_out, codebook; pack tables ----------
// ws layout:
//   WTd  : double[1024][8]   (W_in^T, fp32-rounded widened to f64)  @ 0      (65536 B)
//   cb16 : float [1024][16]  ({cbn[8], scb, pad})                   @ 65536  (65536 B)
//   wo16 : float [1024][16]  ({woutn[8], b_out, pad})               @ 131072 (65536 B)
//   lossp: float [512]                                              @ 196608 (2048 B)
__global__ __launch_bounds__(1024) void vq_setup(
    const float* __restrict__ cb, const float* __restrict__ g_in,
    const float* __restrict__ v_in, const float* __restrict__ g_out,
    const float* __restrict__ v_out, const float* __restrict__ b_out,
    double* __restrict__ WTd, float* __restrict__ cb16,
    float* __restrict__ wo16) {
  __shared__ float sv[8 * 1024];
  __shared__ float leafs[64];
  __shared__ float den[8];
  const int tid = threadIdx.x;

  for (int i = tid; i < 8 * 1024; i += 1024) sv[i] = v_in[i];
  __syncthreads();

  // numpy pairwise_sum(1024): 8 leaf blocks of 128 (8-accumulator pattern),
  // combined with the same binary tree as tree8.
  if (tid < 64) {
    const int c = tid >> 3, l = tid & 7;
    const float* a = sv + c * 1024 + l * 128;
    float r[8];
#pragma unroll
    for (int k = 0; k < 8; ++k) r[k] = __fmul_rn(a[k], a[k]);
    for (int i = 8; i < 128; i += 8) {
#pragma unroll
      for (int k = 0; k < 8; ++k)
        r[k] = __fadd_rn(r[k], __fmul_rn(a[i + k], a[i + k]));
    }
    leafs[c * 8 + l] = f_tree8(r);
  }
  __syncthreads();
  if (tid < 8) {
    const float* L = leafs + tid * 8;
    float lr[8];
#pragma unroll
    for (int k = 0; k < 8; ++k) lr[k] = L[k];
    const float s = f_tree8(lr);
    den[tid] = fmaxf(__fsqrt_rn(s), 1e-12f);
  }
  __syncthreads();

  if (tid < 1024) {
#pragma unroll
    for (int c = 0; c < 8; ++c) {
      const float w = __fdiv_rn(__fmul_rn(g_in[c], sv[c * 1024 + tid]), den[c]);
      WTd[tid * 8 + c] = (double)w;
    }
    {
      const float* cr = cb + tid * 8;
      float q[8];
#pragma unroll
      for (int c = 0; c < 8; ++c) q[c] = cr[c];
      const float nn = f_sumsq8(q);
      const float dd = fmaxf(__fsqrt_rn(nn), 1e-12f);
      float qn[8];
#pragma unroll
      for (int c = 0; c < 8; ++c) {
        qn[c] = __fdiv_rn(q[c], dd);
        cb16[tid * 16 + c] = qn[c];
      }
      cb16[tid * 16 + 8] = f_sumsq8(qn);
#pragma unroll
      for (int c = 9; c < 16; ++c) cb16[tid * 16 + c] = 0.f;
    }
    {
      const float* vr = v_out + tid * 8;
      float w[8];
#pragma unroll
      for (int c = 0; c < 8; ++c) w[c] = vr[c];
      const float n2 = f_sumsq8(w);
      const float d2 = fmaxf(__fsqrt_rn(n2), 1e-12f);
      const float go = g_out[tid];
#pragma unroll
      for (int c = 0; c < 8; ++c)
        wo16[tid * 16 + c] = __fdiv_rn(__fmul_rn(go, w[c]), d2);
      wo16[tid * 16 + 8] = b_out[tid];
#pragma unroll
      for (int c = 9; c < 16; ++c) wo16[tid * 16 + c] = 0.f;
    }
  }
}

// ---------- main kernel ----------
// Grid: 512 blocks x 1024 threads (16 waves). Block owns 128 consecutive t
// of one b; each LANE owns 2 consecutive t (float2 z loads / out stores).
// Wave q (=tid>>6, wave-uniform) covers the same 128 t as the other waves
// but d/code SLICE [q*64, (q+1)*64). Tables via uniform s_load; z via
// explicit 8-deep double-buffered float2 loads (R6-proven). 2 blocks/CU x
// 16 waves = 32 waves/CU = 100% occupancy (VGPR capped at 64 by bounds,
// LDS 64 KB x 2 = 128 <= 160 KB). f64 slice-combine runs in TWO channel
// passes (c0-3, c4-7) through one 64 KB buffer.
__global__ __launch_bounds__(1024, 8) void vq_main(
    const float* __restrict__ z, const float* __restrict__ cbraw,
    const float* __restrict__ b_in, const double* __restrict__ WTd,
    const float* __restrict__ cb16, const float* __restrict__ wo16,
    float* __restrict__ out, float* __restrict__ oidx,
    float* __restrict__ lossp) {
  __shared__ double accb[8192];  // 64 KB: combine (2 passes) + candidates
  const int tid = threadIdx.x;
  const int q0 = __builtin_amdgcn_readfirstlane(tid >> 6);  // wave 0..15
  const int tl = tid & 63;
  const int blk = blockIdx.x;  // 512 = 16 b * 32 tiles
  const int b = blk >> 5;
  const int tile = blk & 31;
  const int t0 = tile * 128 + tl * 2;  // this lane's t-pair

  // ---- phase 1: partial z_e in f64 over this wave's 64-d slice ----
  const float2* zp2 =
      (const float2*)(z + ((size_t)b * D_ + (size_t)q0 * 64) * T_ + t0);
  const double* wd = WTd + (size_t)q0 * 512;  // uniform -> s_load

  double acc0[8], acc1[8];
#pragma unroll
  for (int c = 0; c < 8; ++c) { acc0[c] = 0.0; acc1[c] = 0.0; }

  float2 zA[8], zB[8];
#pragma unroll
  for (int u = 0; u < 8; ++u) zA[u] = zp2[(size_t)u * (T_ / 2)];

#pragma unroll
  for (int dc = 0; dc < 64; dc += 16) {
    // prefetch group B (d = dc+8 .. dc+15)
#pragma unroll
    for (int u = 0; u < 8; ++u)
      zB[u] = zp2[(size_t)(dc + 8 + u) * (T_ / 2)];
    // compute group A
#pragma unroll
    for (int u = 0; u < 8; ++u) {
      const double* w = wd + (size_t)(dc + u) * 8;
      const double zx = (double)zA[u].x, zy = (double)zA[u].y;
#pragma unroll
      for (int c = 0; c < 8; ++c) {
        acc0[c] = fma(zx, w[c], acc0[c]);
        acc1[c] = fma(zy, w[c], acc1[c]);
      }
    }
    // prefetch group A for next chunk
    if (dc + 16 < 64) {
#pragma unroll
      for (int u = 0; u < 8; ++u)
        zA[u] = zp2[(size_t)(dc + 16 + u) * (T_ / 2)];
    }
    // compute group B
#pragma unroll
    for (int u = 0; u < 8; ++u) {
      const double* w = wd + (size_t)(dc + 8 + u) * 8;
      const double zx = (double)zB[u].x, zy = (double)zB[u].y;
#pragma unroll
      for (int c = 0; c < 8; ++c) {
        acc0[c] = fma(zx, w[c], acc0[c]);
        acc1[c] = fma(zy, w[c], acc1[c]);
      }
    }
  }

  // ---- 16-slice f64 combine, two channel passes through 64 KB ----
  double2* accb2 = (double2*)accb;
  double tot0[8], tot1[8];
#pragma unroll
  for (int half = 0; half < 2; ++half) {
    const int cb0 = half * 4;
#pragma unroll
    for (int c = 0; c < 4; ++c) {
      double2 v; v.x = acc0[cb0 + c]; v.y = acc1[cb0 + c];
      accb2[c * 1024 + tid] = v;
    }
    __syncthreads();
#pragma unroll
    for (int c = 0; c < 4; ++c) {
      const double2* row = accb2 + c * 1024 + tl;
      double2 s = row[0];
#pragma unroll
      for (int qq = 1; qq < 16; ++qq) {
        const double2 v = row[qq * 64];
        s.x = s.x + v.x;  // ascending slice order (fixed tree)
        s.y = s.y + v.y;
      }
      tot0[cb0 + c] = s.x; tot1[cb0 + c] = s.y;
    }
    __syncthreads();
  }

  // materialize fp32 z_e (+ b_in), normalize (numpy-mimicked), per t
  float e0[8], e1[8], en0[8], en1[8];
#pragma unroll
  for (int c = 0; c < 8; ++c) {
    e0[c] = __fadd_rn((float)tot0[c], b_in[c]);
    e1[c] = __fadd_rn((float)tot1[c], b_in[c]);
  }
  const float n20 = f_sumsq8(e0), n21 = f_sumsq8(e1);
  const float dn0 = fmaxf(__fsqrt_rn(n20), 1e-12f);
  const float dn1 = fmaxf(__fsqrt_rn(n21), 1e-12f);
#pragma unroll
  for (int c = 0; c < 8; ++c) {
    en0[c] = __fdiv_rn(e0[c], dn0);
    en1[c] = __fdiv_rn(e1[c], dn1);
  }
  const float s_enc0 = f_sumsq8(en0), s_enc1 = f_sumsq8(en1);

  // ---- phase 2: nearest code over this wave's 64-code slice ----
  const int j0 = q0 * 64;
  float best0 = INFINITY, best1 = INFINITY;
  int bj0 = j0, bj1 = j0;
  {
    const float* cbq = cb16 + (size_t)j0 * 16;  // uniform -> s_load
#pragma unroll 4
    for (int jj = 0; jj < 64; ++jj) {
      const float* row = cbq + jj * 16;
      const float4 lo = *(const float4*)(row);
      const float4 hi = *(const float4*)(row + 4);
      const float sc = row[8];
      float d0 = 0.f, d1 = 0.f;
      d0 = fmaf(en0[0], lo.x, d0); d1 = fmaf(en1[0], lo.x, d1);
      d0 = fmaf(en0[1], lo.y, d0); d1 = fmaf(en1[1], lo.y, d1);
      d0 = fmaf(en0[2], lo.z, d0); d1 = fmaf(en1[2], lo.z, d1);
      d0 = fmaf(en0[3], lo.w, d0); d1 = fmaf(en1[3], lo.w, d1);
      d0 = fmaf(en0[4], hi.x, d0); d1 = fmaf(en1[4], hi.x, d1);
      d0 = fmaf(en0[5], hi.y, d0); d1 = fmaf(en1[5], hi.y, d1);
      d0 = fmaf(en0[6], hi.z, d0); d1 = fmaf(en1[6], hi.z, d1);
      d0 = fmaf(en0[7], hi.w, d0); d1 = fmaf(en1[7], hi.w, d1);
      const float dist0 =
          __fadd_rn(__fsub_rn(s_enc0, __fmul_rn(2.0f, d0)), sc);
      const float dist1 =
          __fadd_rn(__fsub_rn(s_enc1, __fmul_rn(2.0f, d1)), sc);
      if (dist0 < best0) { best0 = dist0; bj0 = j0 + jj; }
      if (dist1 < best1) { best1 = dist1; bj1 = j0 + jj; }
    }
  }

  // candidate combine (SoA in reused LDS; 4B stride: conflict-free)
  float* distf0 = (float*)accb;                  // 1024 f32
  int* candj0 = (int*)((char*)accb + 4096);      // 1024 i32
  float* distf1 = (float*)((char*)accb + 8192);  // 1024 f32
  int* candj1 = (int*)((char*)accb + 12288);     // 1024 i32
  distf0[tid] = best0; candj0[tid] = bj0;
  distf1[tid] = best1; candj1[tid] = bj1;
  __syncthreads();

  float bd0 = distf0[tl], bd1 = distf1[tl];
  int bi0 = candj0[tl], bi1 = candj1[tl];
#pragma unroll
  for (int qq = 1; qq < 16; ++qq) {
    const float dd0 = distf0[qq * 64 + tl];
    const int jj0v = candj0[qq * 64 + tl];
    if (dd0 < bd0) { bd0 = dd0; bi0 = jj0v; }  // strict <: low slice wins
    const float dd1 = distf1[qq * 64 + tl];
    const int jj1v = candj1[qq * 64 + tl];
    if (dd1 < bd1) { bd1 = dd1; bi1 = jj1v; }
  }

  if (tid < 64) {
    float2 iv; iv.x = (float)bi0; iv.y = (float)bi1;
    *(float2*)(oidx + (size_t)b * T_ + t0) = iv;
  }

  // raw codebook rows for loss + back-projection (divergent 32B gathers)
  float cq0[8], cq1[8];
  {
    const float* cp0 = cbraw + (size_t)bi0 * 8;
    const float* cp1 = cbraw + (size_t)bi1 * 8;
#pragma unroll
    for (int c = 0; c < 8; ++c) { cq0[c] = cp0[c]; cq1[c] = cp1[c]; }
  }

  // ---- loss partial (wave 0 only; all waves hold identical e, cq) ----
  if (tid < 64) {
    float lsum = 0.f;
#pragma unroll
    for (int c = 0; c < 8; ++c) {
      const float df0 = __fsub_rn(e0[c], cq0[c]);
      lsum = fmaf(df0, df0, lsum);
    }
#pragma unroll
    for (int c = 0; c < 8; ++c) {
      const float df1 = __fsub_rn(e1[c], cq1[c]);
      lsum = fmaf(df1, df1, lsum);
    }
#pragma unroll
    for (int off = 32; off > 0; off >>= 1)
      lsum += __shfl_down(lsum, off, 64);
    if (tl == 0) lossp[blk] = lsum;
  }

  // ---- phase 3: out[b,d,{t0,t0+1}] over this wave's 64-d slice ----
  float2* op2 =
      (float2*)(out + ((size_t)b * D_ + (size_t)q0 * 64) * T_ + t0);
  const float* woq = wo16 + (size_t)q0 * 1024;  // uniform -> s_load
#pragma unroll 4
  for (int d = 0; d < 64; ++d) {
    const float* row = woq + d * 16;
    const float4 lo = *(const float4*)(row);
    const float4 hi = *(const float4*)(row + 4);
    const float bo = row[8];
    float d0 = 0.f, d1 = 0.f;
    d0 = fmaf(cq0[0], lo.x, d0); d1 = fmaf(cq1[0], lo.x, d1);
    d0 = fmaf(cq0[1], lo.y, d0); d1 = fmaf(cq1[1], lo.y, d1);
    d0 = fmaf(cq0[2], lo.z, d0); d1 = fmaf(cq1[2], lo.z, d1);
    d0 = fmaf(cq0[3], lo.w, d0); d1 = fmaf(cq1[3], lo.w, d1);
    d0 = fmaf(cq0[4], hi.x, d0); d1 = fmaf(cq1[4], hi.x, d1);
    d0 = fmaf(cq0[5], hi.y, d0); d1 = fmaf(cq1[5], hi.y, d1);
    d0 = fmaf(cq0[6], hi.z, d0); d1 = fmaf(cq1[6], hi.z, d1);
    d0 = fmaf(cq0[7], hi.w, d0); d1 = fmaf(cq1[7], hi.w, d1);
    float2 ov; ov.x = __fadd_rn(d0, bo); ov.y = __fadd_rn(d1, bo);
    op2[(size_t)d * (T_ / 2)] = ov;
  }
}

// ---------- finalize loss ----------
__global__ __launch_bounds__(64) void vq_fin(const float* __restrict__ lossp,
                                             float* __restrict__ oloss) {
  const int tid = threadIdx.x;
  if (tid < B_) {
    float s = 0.f;
    for (int i = 0; i < 32; ++i) s += lossp[tid * 32 + i];
    oloss[tid] = s * (1.25f / 32768.0f);
  }
}

extern "C" void kernel_launch(void* const* d_in, const int* in_sizes, int n_in,
                              void* d_out, int out_size, void* d_ws,
                              size_t ws_size, hipStream_t stream) {
  (void)in_sizes; (void)n_in; (void)out_size; (void)ws_size;
  const float* z = (const float*)d_in[0];
  const float* cb = (const float*)d_in[1];
  const float* g_in = (const float*)d_in[2];
  const float* v_in = (const float*)d_in[3];
  const float* b_in = (const float*)d_in[4];
  const float* g_out = (const float*)d_in[5];
  const float* v_out = (const float*)d_in[6];
  const float* b_out = (const float*)d_in[7];
  float* out = (float*)d_out;

  char* ws = (char*)d_ws;
  double* WTd = (double*)ws;              // 65536 B
  float* cb16 = (float*)(ws + 65536);     // 65536 B
  float* wo16 = (float*)(ws + 131072);    // 65536 B
  float* lossp = (float*)(ws + 196608);   // 2048 B

  float* oidx = out + (size_t)B_ * D_ * T_;
  float* oloss = oidx + (size_t)B_ * T_;

  vq_setup<<<1, 1024, 0, stream>>>(cb, g_in, v_in, g_out, v_out, b_out, WTd,
                                   cb16, wo16);
  vq_main<<<512, 1024, 0, stream>>>(z, cb, b_in, WTd, cb16, wo16, out, oidx,
                                    lossp);
  vq_fin<<<1, 64, 0, stream>>>(lossp, oloss);
}